// Round 5
// baseline (468.130 us; speedup 1.0000x reference)
//
#include <hip/hip_runtime.h>
#include <math.h>

#define BSZ   2048
#define INDIM 1024
#define QDIM  2048   // HEADS*K_DIM
#define NHT   8      // HEADS*2
#define NKEYS 512
#define HALFD 256
#define KNN   32
#define VDIM  1024
#define HEADS 4

typedef _Float16 v8h __attribute__((ext_vector_type(8)));
typedef _Float16 v4h __attribute__((ext_vector_type(4)));
typedef float    v4f __attribute__((ext_vector_type(4)));

// ---------- f32 -> {h, h/64, m=64*(a-h)} f16 plane split ----------
// A-side plane order: [h, h/64, m]; B-side: [h, m, h/64]
template<int KSHIFT, bool ASIDE>
__device__ __forceinline__ void split4(const float* __restrict__ in,
                                       _Float16* __restrict__ out, int i) {
  const long e0 = (long)i * 4;
  const int K = 1 << KSHIFT;
  const long r = e0 >> KSHIFT;
  const int k = (int)(e0 & (K - 1));
  const float4 a = *(const float4*)&in[e0];
  const float av[4] = {a.x, a.y, a.z, a.w};
  v4h hv, dv, mv;
  #pragma unroll
  for (int u = 0; u < 4; ++u) {
    const _Float16 hh = (_Float16)av[u];
    hv[u] = hh;
    mv[u] = (_Float16)((av[u] - (float)hh) * 64.0f);
    dv[u] = (_Float16)((float)hh * 0.015625f);
  }
  _Float16* base = out + r * (3L * K) + k;
  *(v4h*)(base)         = hv;
  *(v4h*)(base + K)     = ASIDE ? dv : mv;
  *(v4h*)(base + 2 * K) = ASIDE ? mv : dv;
}

__global__ __launch_bounds__(256) void split_all_kernel(
    const float* __restrict__ x, const float* __restrict__ wq, const float* __restrict__ ky,
    _Float16* __restrict__ xs, _Float16* __restrict__ wqs, _Float16* __restrict__ kys) {
  const int i = blockIdx.x * 256 + threadIdx.x;
  if (i < 524288)            split4<10, true >(x,  xs,  i);
  else if (i < 1048576)      split4<10, false>(wq, wqs, i - 524288);
  else                       split4<8,  false>(ky, kys, i - 1048576);
}

// ---------- async global->LDS 16B ----------
__device__ __forceinline__ void gload16(const _Float16* g, _Float16* l) {
  __builtin_amdgcn_global_load_lds(
      (const __attribute__((address_space(1))) unsigned int*)g,
      (__attribute__((address_space(3))) unsigned int*)l, 16, 0, 0);
}

// =================== GEMM1: Q'' = split(xs @ wqs^T + b) ===================
// 128x128 tile, BK=64, 2-phase dbuf, 256 threads. K=3072, lda=ldb=3072.
// LDS swizzle: byte ^= ((byte>>7)&7)<<4 within [rows][128B] tiles.
__global__ __launch_bounds__(256) void gemm1_kernel(
    const _Float16* __restrict__ A, const _Float16* __restrict__ B,
    const float* __restrict__ bias, _Float16* __restrict__ Cq) {
  __shared__ __align__(16) char smem[65536];
  _Float16* sh = (_Float16*)smem;
  const int t = threadIdx.x;
  const int m0 = blockIdx.y * 128, n0 = blockIdx.x * 128;
  const int lane = t & 63, w = t >> 6;
  const int wr = (w >> 1) * 64, wc = (w & 1) * 64;
  const int fr = lane & 15, kg = lane >> 4;

  // staging sources (inverse-swizzled) + linear LDS dests
  const _Float16* gA[4]; const _Float16* gB[4];
  int dA[4], dB[4];
  #pragma unroll
  for (int p = 0; p < 4; ++p) {
    const int O = p * 4096 + t * 16;
    const int os = O ^ (((O >> 7) & 7) << 4);
    const int srow = os >> 7, sk = (os & 127) >> 1;
    gA[p] = A + (size_t)(m0 + srow) * 3072 + sk;
    gB[p] = B + (size_t)(n0 + srow) * 3072 + sk;
    dA[p] = O >> 1;
    dB[p] = (16384 + O) >> 1;
  }

  // fragment read offsets (swizzled)
  int aof[2][4], bof[2][4];
  #pragma unroll
  for (int ks = 0; ks < 2; ++ks)
    #pragma unroll
    for (int i = 0; i < 4; ++i) {
      const int ra = wr + i * 16 + fr;
      aof[ks][i] = (ra * 128 + ((((ks << 2) | kg) ^ (fr & 7)) << 4)) >> 1;
      const int rb = wc + i * 16 + fr;
      bof[ks][i] = ((rb * 128 + ((((ks << 2) | kg) ^ (fr & 7)) << 4)) >> 1) + 8192;
    }

  v4f acc[4][4];
  #pragma unroll
  for (int i = 0; i < 4; ++i)
    #pragma unroll
    for (int j = 0; j < 4; ++j)
      acc[i][j] = (v4f){0.f, 0.f, 0.f, 0.f};

  // prologue
  #pragma unroll
  for (int p = 0; p < 4; ++p) { gload16(gA[p], sh + dA[p]); gload16(gB[p], sh + dB[p]); }
  __syncthreads();

  int cur = 0;
  for (int kt = 0; kt < 3072; kt += 64) {
    if (kt + 64 < 3072) {
      _Float16* bb = sh + (cur ^ 1) * 16384;
      #pragma unroll
      for (int p = 0; p < 4; ++p) {
        gload16(gA[p] + kt + 64, bb + dA[p]);
        gload16(gB[p] + kt + 64, bb + dB[p]);
      }
    }
    const _Float16* bb = sh + cur * 16384;
    #pragma unroll
    for (int ks = 0; ks < 2; ++ks) {
      v8h af[4], bf[4];
      #pragma unroll
      for (int i = 0; i < 4; ++i) af[i] = *(const v8h*)(bb + aof[ks][i]);
      #pragma unroll
      for (int j = 0; j < 4; ++j) bf[j] = *(const v8h*)(bb + bof[ks][j]);
      #pragma unroll
      for (int i = 0; i < 4; ++i)
        #pragma unroll
        for (int j = 0; j < 4; ++j)
          acc[i][j] = __builtin_amdgcn_mfma_f32_16x16x32_f16(af[i], bf[j], acc[i][j], 0, 0, 0);
    }
    __syncthreads();
    cur ^= 1;
  }

  // epilogue: bias + 3-plane f16 split, via LDS transpose (two 64-col halves)
  float* Ct = (float*)smem;
  #pragma unroll
  for (int half = 0; half < 2; ++half) {
    __syncthreads();
    if ((w & 1) == half) {
      #pragma unroll
      for (int j = 0; j < 4; ++j) {
        const int colq = j * 16 + fr;
        const float bv = bias[n0 + half * 64 + colq];
        #pragma unroll
        for (int i = 0; i < 4; ++i)
          #pragma unroll
          for (int rr = 0; rr < 4; ++rr)
            Ct[(wr + i * 16 + kg * 4 + rr) * 68 + colq] = acc[i][j][rr] + bv;
      }
    }
    __syncthreads();
    const int r = t >> 1, cb = (t & 1) * 32;
    const int gcol = n0 + half * 64 + cb;
    const int ht = gcol >> 8, dd = gcol & 255;
    _Float16* p = Cq + (size_t)(m0 + r) * (3 * HALFD * NHT) + ht * (3 * HALFD) + dd;
    #pragma unroll
    for (int u = 0; u < 32; u += 8) {
      float vv[8];
      *(float4*)&vv[0] = *(const float4*)&Ct[r * 68 + cb + u];
      *(float4*)&vv[4] = *(const float4*)&Ct[r * 68 + cb + u + 4];
      v8h hv, dv, mv;
      #pragma unroll
      for (int e = 0; e < 8; ++e) {
        const _Float16 hh = (_Float16)vv[e];
        hv[e] = hh;
        mv[e] = (_Float16)((vv[e] - (float)hh) * 64.0f);
        dv[e] = (_Float16)((float)hh * 0.015625f);
      }
      *(v8h*)(p + u) = hv;
      *(v8h*)(p + HALFD + u) = dv;
      *(v8h*)(p + 2 * HALFD + u) = mv;
    }
  }
}

// ============ GEMM2 + topk1 fused: scores + per-row top-32 ============
// Block: 64 rows x 512 cols, one ht. 512 threads (8 waves), BK=64 dbuf.
__global__ __launch_bounds__(512) void gemm2_topk_kernel(
    const _Float16* __restrict__ Qs, const _Float16* __restrict__ Ks,
    float* __restrict__ sTop, int* __restrict__ iTop) {
  __shared__ __align__(16) char smem[147456];   // 2 x (A 8KB + B 64KB); scores overlay 129KB
  __shared__ float sels[8][32];
  __shared__ int   seli[8][32];
  _Float16* sh = (_Float16*)smem;
  const int t = threadIdx.x;
  const int m0 = blockIdx.x * 64;
  const int ht = blockIdx.y;
  const _Float16* Ab = Qs + (size_t)ht * 768;           // lda 6144
  const _Float16* Bb = Ks + (size_t)ht * 512 * 768;     // ldb 768
  const int lane = t & 63, w = t >> 6;
  const int fr = lane & 15, kg = lane >> 4;
  const int wc = w * 64;

  // staging: A one 8KB pass, B eight 8KB passes
  const int OA = t * 16;
  const int osA = OA ^ (((OA >> 7) & 7) << 4);
  const _Float16* gA = Ab + (size_t)(m0 + (osA >> 7)) * 6144 + ((osA & 127) >> 1);
  const int dA = OA >> 1;
  const _Float16* gB[8]; int dB[8];
  #pragma unroll
  for (int p = 0; p < 8; ++p) {
    const int O = p * 8192 + t * 16;
    const int os = O ^ (((O >> 7) & 7) << 4);
    gB[p] = Bb + (size_t)(os >> 7) * 768 + ((os & 127) >> 1);
    dB[p] = (8192 + O) >> 1;
  }

  int aof[2][4], bof[2][4];
  #pragma unroll
  for (int ks = 0; ks < 2; ++ks)
    #pragma unroll
    for (int i = 0; i < 4; ++i) {
      const int ra = i * 16 + fr;
      aof[ks][i] = (ra * 128 + ((((ks << 2) | kg) ^ (fr & 7)) << 4)) >> 1;
      const int rb = wc + i * 16 + fr;
      bof[ks][i] = ((rb * 128 + ((((ks << 2) | kg) ^ (fr & 7)) << 4)) >> 1) + 4096;
    }

  v4f acc[4][4];
  #pragma unroll
  for (int i = 0; i < 4; ++i)
    #pragma unroll
    for (int j = 0; j < 4; ++j)
      acc[i][j] = (v4f){0.f, 0.f, 0.f, 0.f};

  gload16(gA, sh + dA);
  #pragma unroll
  for (int p = 0; p < 8; ++p) gload16(gB[p], sh + dB[p]);
  __syncthreads();

  int cur = 0;
  for (int kt = 0; kt < 768; kt += 64) {
    if (kt + 64 < 768) {
      _Float16* bb = sh + (cur ^ 1) * 36864;
      gload16(gA + kt + 64, bb + dA);
      #pragma unroll
      for (int p = 0; p < 8; ++p) gload16(gB[p] + kt + 64, bb + dB[p]);
    }
    const _Float16* bb = sh + cur * 36864;
    #pragma unroll
    for (int ks = 0; ks < 2; ++ks) {
      v8h af[4], bf[4];
      #pragma unroll
      for (int i = 0; i < 4; ++i) af[i] = *(const v8h*)(bb + aof[ks][i]);
      #pragma unroll
      for (int j = 0; j < 4; ++j) bf[j] = *(const v8h*)(bb + bof[ks][j]);
      #pragma unroll
      for (int i = 0; i < 4; ++i)
        #pragma unroll
        for (int j = 0; j < 4; ++j)
          acc[i][j] = __builtin_amdgcn_mfma_f32_16x16x32_f16(af[i], bf[j], acc[i][j], 0, 0, 0);
    }
    __syncthreads();
    cur ^= 1;
  }

  // scores -> LDS [64][516 f32] (padded stride), then per-row top-32
  float* Sl = (float*)smem;
  #pragma unroll
  for (int i = 0; i < 4; ++i)
    #pragma unroll
    for (int j = 0; j < 4; ++j)
      #pragma unroll
      for (int rr = 0; rr < 4; ++rr)
        Sl[(i * 16 + kg * 4 + rr) * 516 + wc + j * 16 + fr] = acc[i][j][rr];
  __syncthreads();

  for (int rw = 0; rw < 8; ++rw) {
    const int row = w * 8 + rw;
    float v[8];
    #pragma unroll
    for (int jj = 0; jj < 8; ++jj) v[jj] = Sl[row * 516 + jj * 64 + lane];
    for (int r = 0; r < KNN; ++r) {
      float bv = -INFINITY; int bi = 0x7fffffff;
      #pragma unroll
      for (int jj = 0; jj < 8; ++jj) {
        const int idx = jj * 64 + lane;
        if (v[jj] > bv) { bv = v[jj]; bi = idx; }
      }
      #pragma unroll
      for (int off = 32; off > 0; off >>= 1) {
        const float ov = __shfl_xor(bv, off);
        const int oi = __shfl_xor(bi, off);
        if (ov > bv || (ov == bv && oi < bi)) { bv = ov; bi = oi; }
      }
      if (lane == 0) { sels[w][r] = bv; seli[w][r] = bi; }
      const int jj0 = bi >> 6;
      const bool mine = (bi & 63) == lane;
      #pragma unroll
      for (int jj = 0; jj < 8; ++jj)
        if (mine && jj == jj0) v[jj] = -INFINITY;
    }
    if (lane < 32) {
      const size_t ro = ((size_t)(m0 + row) * NHT + ht) * KNN;
      sTop[ro + lane] = sels[w][lane];
      iTop[ro + lane] = seli[w][lane];
    }
  }
}

// ============ topk2 + softmax + gather fused (one block per token) ============
__global__ __launch_bounds__(256) void topk2_gather_kernel(
    const float* __restrict__ sTop, const int* __restrict__ iTop,
    const float* __restrict__ values, float* __restrict__ out) {
  __shared__ float ls1[4][32], ls2[4][32], sels[4][32];
  __shared__ int   li1[4][32], li2[4][32], seli[4][32];
  __shared__ float lw[128];
  __shared__ int   lidx[128];
  const int b = blockIdx.x, t = threadIdx.x;
  const int lane = t & 63, h = t >> 6;
  const size_t r1 = ((size_t)b * NHT + 2 * h) * KNN;
  if (lane < 32) {
    ls1[h][lane] = sTop[r1 + lane];        li1[h][lane] = iTop[r1 + lane];
    ls2[h][lane] = sTop[r1 + KNN + lane];  li2[h][lane] = iTop[r1 + KNN + lane];
  }
  float v[16];
  #pragma unroll
  for (int c = 0; c < 16; ++c) {
    const int p = c * 64 + lane;
    v[c] = ls1[h][p >> 5] + ls2[h][p & 31];
  }
  for (int r = 0; r < KNN; ++r) {
    float bv = -INFINITY; int bp = 0x7fffffff;
    #pragma unroll
    for (int c = 0; c < 16; ++c) {
      const int p = c * 64 + lane;
      if (v[c] > bv) { bv = v[c]; bp = p; }
    }
    #pragma unroll
    for (int off = 32; off > 0; off >>= 1) {
      const float ov = __shfl_xor(bv, off);
      const int op = __shfl_xor(bp, off);
      if (ov > bv || (ov == bv && op < bp)) { bv = ov; bp = op; }
    }
    if (lane == 0) {
      sels[h][r] = bv;
      seli[h][r] = li1[h][bp >> 5] * NKEYS + li2[h][bp & 31];
    }
    const int cc = bp >> 6;
    const bool mine = (bp & 63) == lane;
    #pragma unroll
    for (int c = 0; c < 16; ++c)
      if (mine && c == cc) v[c] = -INFINITY;
  }
  const float m = sels[h][0];
  const float e = (lane < 32) ? expf(sels[h][lane] - m) : 0.0f;
  float s = e;
  #pragma unroll
  for (int off = 32; off > 0; off >>= 1) s += __shfl_xor(s, off);
  if (lane < 32) {
    lw[h * 32 + lane] = e / s;
    lidx[h * 32 + lane] = seli[h][lane];
  }
  __syncthreads();
  // gather
  const int d0 = t * 4;
  float4 acc = {0.f, 0.f, 0.f, 0.f};
  #pragma unroll 8
  for (int k = 0; k < 128; ++k) {
    const float4 vv = *(const float4*)&values[(size_t)lidx[k] * VDIM + d0];
    const float ww = lw[k];
    acc.x = fmaf(ww, vv.x, acc.x);
    acc.y = fmaf(ww, vv.y, acc.y);
    acc.z = fmaf(ww, vv.z, acc.z);
    acc.w = fmaf(ww, vv.w, acc.w);
  }
  *(float4*)&out[(size_t)b * VDIM + d0] = acc;
}

extern "C" void kernel_launch(void* const* d_in, const int* in_sizes, int n_in,
                              void* d_out, int out_size, void* d_ws, size_t ws_size,
                              hipStream_t stream) {
  const float* x      = (const float*)d_in[0];
  const float* w_q    = (const float*)d_in[1];
  const float* b_q    = (const float*)d_in[2];
  const float* keys   = (const float*)d_in[3];
  const float* values = (const float*)d_in[4];
  float* out = (float*)d_out;

  char* ws = (char*)d_ws;
  _Float16* xs    = (_Float16*)(ws);                  // 2048*3072*2 = 12.6 MB
  _Float16* wqs   = (_Float16*)(ws + (16u << 20));    // 12.6 MB
  _Float16* keyss = (_Float16*)(ws + (32u << 20));    // 4096*768*2 = 6.3 MB
  _Float16* Qs    = (_Float16*)(ws + (40u << 20));    // 2048*6144*2 = 25.2 MB
  float*    sTop  = (float*)   (ws + (68u << 20));    // 16384*32*4 = 2 MB
  int*      iTop  = (int*)     (ws + (70u << 20));    // 2 MB

  split_all_kernel<<<5120, 256, 0, stream>>>(x, w_q, keys, xs, wqs, keyss);
  gemm1_kernel<<<dim3(QDIM / 128, BSZ / 128), 256, 0, stream>>>(xs, wqs, b_q, Qs);
  gemm2_topk_kernel<<<dim3(BSZ / 64, NHT), 512, 0, stream>>>(Qs, keyss, sTop, iTop);
  topk2_gather_kernel<<<BSZ, 256, 0, stream>>>(sTop, iTop, values, out);
}

// Round 6
// 377.012 us; speedup vs baseline: 1.2417x; 1.2417x over previous
//
#include <hip/hip_runtime.h>
#include <math.h>

#define BSZ   2048
#define INDIM 1024
#define QDIM  2048   // HEADS*K_DIM
#define NHT   8      // HEADS*2
#define NKEYS 512
#define HALFD 256
#define KNN   32
#define VDIM  1024
#define HEADS 4

typedef _Float16 v8h __attribute__((ext_vector_type(8)));
typedef _Float16 v4h __attribute__((ext_vector_type(4)));
typedef float    v4f __attribute__((ext_vector_type(4)));

// ---------- f32 -> {h, h/64, m=64*(a-h)} f16 plane split ----------
// A-side plane order: [h, h/64, m]; B-side: [h, m, h/64]
template<int KSHIFT, bool ASIDE>
__device__ __forceinline__ void split4(const float* __restrict__ in,
                                       _Float16* __restrict__ out, int i) {
  const long e0 = (long)i * 4;
  const int K = 1 << KSHIFT;
  const long r = e0 >> KSHIFT;
  const int k = (int)(e0 & (K - 1));
  const float4 a = *(const float4*)&in[e0];
  const float av[4] = {a.x, a.y, a.z, a.w};
  v4h hv, dv, mv;
  #pragma unroll
  for (int u = 0; u < 4; ++u) {
    const _Float16 hh = (_Float16)av[u];
    hv[u] = hh;
    mv[u] = (_Float16)((av[u] - (float)hh) * 64.0f);
    dv[u] = (_Float16)((float)hh * 0.015625f);
  }
  _Float16* base = out + r * (3L * K) + k;
  *(v4h*)(base)         = hv;
  *(v4h*)(base + K)     = ASIDE ? dv : mv;
  *(v4h*)(base + 2 * K) = ASIDE ? mv : dv;
}

__global__ __launch_bounds__(256) void split_all_kernel(
    const float* __restrict__ x, const float* __restrict__ wq, const float* __restrict__ ky,
    _Float16* __restrict__ xs, _Float16* __restrict__ wqs, _Float16* __restrict__ kys) {
  const int i = blockIdx.x * 256 + threadIdx.x;
  if (i < 524288)            split4<10, true >(x,  xs,  i);
  else if (i < 1048576)      split4<10, false>(wq, wqs, i - 524288);
  else                       split4<8,  false>(ky, kys, i - 1048576);
}

// ---------- async global->LDS 16B ----------
__device__ __forceinline__ void gload16(const _Float16* g, _Float16* l) {
  __builtin_amdgcn_global_load_lds(
      (const __attribute__((address_space(1))) unsigned int*)g,
      (__attribute__((address_space(3))) unsigned int*)l, 16, 0, 0);
}

// ---------- f16 MFMA GEMM, 128x128 tile, BK=32, 2-phase dbuf, C = A @ B^T ----------
// Q_EPI: bias + 3-plane f16 epilogue (LDS-transposed, vectorized stores).
template<bool Q_EPI>
__global__ __launch_bounds__(256) void mfma_gemm(
    const _Float16* __restrict__ A, int lda, long aBS,
    const _Float16* __restrict__ B, int ldb, long bBS,
    const float* __restrict__ bias,
    float* __restrict__ Cf, int ldc, long cBS,
    _Float16* __restrict__ Cq, int K) {
  extern __shared__ __align__(16) char smem[];
  _Float16* Asm = (_Float16*)smem;             // [2][4096] f16 = 16 KB
  _Float16* Bsm = (_Float16*)(smem + 16384);   // [2][4096] f16 = 16 KB
  const int t = threadIdx.x;
  const int z = blockIdx.z;
  const _Float16* Ab = A + (size_t)z * aBS;
  const _Float16* Bb = B + (size_t)z * bBS;
  const int m0 = blockIdx.y * 128, n0 = blockIdx.x * 128;

  // staging: LDS dest linear (t*16 B within 4KB half); global source inverse-swizzled
  // swizzle: byte ^= ((byte>>7)&3)<<4
  const int o0 = t * 16;
  const int os = o0 ^ (((o0 >> 7) & 3) << 4);
  const int sr = os >> 6;            // source row within 64-row half
  const int sk = (os & 63) >> 1;     // source k element (0..31)
  const _Float16* gA0 = Ab + (size_t)(m0 + sr) * lda + sk;
  const _Float16* gA1 = Ab + (size_t)(m0 + sr + 64) * lda + sk;
  const _Float16* gB0 = Bb + (size_t)(n0 + sr) * ldb + sk;
  const _Float16* gB1 = Bb + (size_t)(n0 + sr + 64) * ldb + sk;

  const int lane = t & 63, w = t >> 6;
  const int wr = (w >> 1) * 64, wc = (w & 1) * 64;
  const int fr = lane & 15, kg = lane >> 4;

  int aoff[4], boff[4];
  #pragma unroll
  for (int i = 0; i < 4; ++i) {
    const int ra = wr + i * 16 + fr;
    aoff[i] = (ra * 64 + ((kg ^ ((ra >> 1) & 3)) * 16)) >> 1;
    const int rb = wc + i * 16 + fr;
    boff[i] = (rb * 64 + ((kg ^ ((rb >> 1) & 3)) * 16)) >> 1;
  }

  v4f acc[4][4];
  #pragma unroll
  for (int i = 0; i < 4; ++i)
    #pragma unroll
    for (int j = 0; j < 4; ++j)
      acc[i][j] = (v4f){0.f, 0.f, 0.f, 0.f};

  // prologue: stage tile 0 into buf 0
  gload16(gA0, Asm + t * 8);
  gload16(gA1, Asm + 2048 + t * 8);
  gload16(gB0, Bsm + t * 8);
  gload16(gB1, Bsm + 2048 + t * 8);
  __syncthreads();

  int cur = 0;
  for (int kt = 0; kt < K; kt += 32) {
    const int nxt = cur ^ 1;
    if (kt + 32 < K) {   // issue next-tile loads FIRST (overlap with compute)
      gload16(gA0 + kt + 32, Asm + nxt * 4096 + t * 8);
      gload16(gA1 + kt + 32, Asm + nxt * 4096 + 2048 + t * 8);
      gload16(gB0 + kt + 32, Bsm + nxt * 4096 + t * 8);
      gload16(gB1 + kt + 32, Bsm + nxt * 4096 + 2048 + t * 8);
    }
    v8h af[4], bf[4];
    #pragma unroll
    for (int i = 0; i < 4; ++i) af[i] = *(const v8h*)(Asm + cur * 4096 + aoff[i]);
    #pragma unroll
    for (int j = 0; j < 4; ++j) bf[j] = *(const v8h*)(Bsm + cur * 4096 + boff[j]);
    #pragma unroll
    for (int i = 0; i < 4; ++i)
      #pragma unroll
      for (int j = 0; j < 4; ++j)
        acc[i][j] = __builtin_amdgcn_mfma_f32_16x16x32_f16(af[i], bf[j], acc[i][j], 0, 0, 0);
    __syncthreads();   // next tile landed; readers done before overwrite
    cur = nxt;
  }

  // C/D map (16x16x32): col = lane&15, row = (lane>>4)*4 + reg
  if (Q_EPI) {
    // two 64-col passes through LDS [128][68] f32 (34816 B)
    float* Ct = (float*)smem;
    #pragma unroll
    for (int half = 0; half < 2; ++half) {
      __syncthreads();
      if ((w & 1) == half) {
        #pragma unroll
        for (int j = 0; j < 4; ++j) {
          const int colq = j * 16 + fr;          // 0..63 within half
          const float bv = bias[n0 + half * 64 + colq];
          #pragma unroll
          for (int i = 0; i < 4; ++i)
            #pragma unroll
            for (int rr = 0; rr < 4; ++rr)
              Ct[(wr + i * 16 + kg * 4 + rr) * 68 + colq] = acc[i][j][rr] + bv;
        }
      }
      __syncthreads();
      const int r = t >> 1, cb = (t & 1) * 32;
      const int gcol = n0 + half * 64 + cb;      // 32-aligned
      const int ht = gcol >> 8, dd = gcol & 255;
      _Float16* p = Cq + (size_t)(m0 + r) * (3 * HALFD * NHT) + ht * (3 * HALFD) + dd;
      #pragma unroll
      for (int u = 0; u < 32; u += 8) {
        float vv[8];
        *(float4*)&vv[0] = *(const float4*)&Ct[r * 68 + cb + u];
        *(float4*)&vv[4] = *(const float4*)&Ct[r * 68 + cb + u + 4];
        v8h hv, dv, mv;
        #pragma unroll
        for (int e = 0; e < 8; ++e) {
          const _Float16 hh = (_Float16)vv[e];
          hv[e] = hh;
          mv[e] = (_Float16)((vv[e] - (float)hh) * 64.0f);
          dv[e] = (_Float16)((float)hh * 0.015625f);
        }
        *(v8h*)(p + u) = hv;                    // h
        *(v8h*)(p + HALFD + u) = dv;            // h/64
        *(v8h*)(p + 2 * HALFD + u) = mv;        // m
      }
    }
  } else {
    float* Cb = Cf + (size_t)z * cBS;
    #pragma unroll
    for (int i = 0; i < 4; ++i)
      #pragma unroll
      for (int j = 0; j < 4; ++j)
        #pragma unroll
        for (int rr = 0; rr < 4; ++rr) {
          const int rowg = m0 + wr + i * 16 + kg * 4 + rr;
          const int colg = n0 + wc + j * 16 + fr;
          Cb[(size_t)rowg * ldc + colg] = acc[i][j][rr];
        }
  }
}

// ---------------- top-32 of 512 per row; ties -> smallest index ----------------
__global__ __launch_bounds__(64) void topk1_kernel(
    const float* __restrict__ S, float* __restrict__ sTop, int* __restrict__ iTop) {
  const int row = blockIdx.x;           // b*8 + ht
  const int lane = threadIdx.x;
  const float* sr = S + (size_t)row * NKEYS;
  float v[8];
  #pragma unroll
  for (int j = 0; j < 8; ++j) v[j] = sr[j * 64 + lane];
  for (int r = 0; r < KNN; ++r) {
    float bv = -INFINITY; int bi = 0x7fffffff;
    #pragma unroll
    for (int j = 0; j < 8; ++j) {
      int idx = j * 64 + lane;
      if (v[j] > bv) { bv = v[j]; bi = idx; }
    }
    #pragma unroll
    for (int off = 32; off > 0; off >>= 1) {
      float ov = __shfl_xor(bv, off);
      int oi = __shfl_xor(bi, off);
      if (ov > bv || (ov == bv && oi < bi)) { bv = ov; bi = oi; }
    }
    if (lane == 0) { sTop[(size_t)row * KNN + r] = bv; iTop[(size_t)row * KNN + r] = bi; }
    const int jj = bi >> 6;
    const bool mine = (bi & 63) == lane;
    #pragma unroll
    for (int j = 0; j < 8; ++j)
      if (mine && j == jj) v[j] = -INFINITY;
  }
}

// ============ topk2 + softmax + gather fused (one block per token) ============
__global__ __launch_bounds__(256) void topk2_gather_kernel(
    const float* __restrict__ sTop, const int* __restrict__ iTop,
    const float* __restrict__ values, float* __restrict__ out) {
  __shared__ float ls1[4][32], ls2[4][32], sels[4][32];
  __shared__ int   li1[4][32], li2[4][32], seli[4][32];
  __shared__ float lw[128];
  __shared__ int   lidx[128];
  const int b = blockIdx.x, t = threadIdx.x;
  const int lane = t & 63, h = t >> 6;
  const size_t r1 = ((size_t)b * NHT + 2 * h) * KNN;
  if (lane < 32) {
    ls1[h][lane] = sTop[r1 + lane];        li1[h][lane] = iTop[r1 + lane];
    ls2[h][lane] = sTop[r1 + KNN + lane];  li2[h][lane] = iTop[r1 + KNN + lane];
  }
  float v[16];
  #pragma unroll
  for (int c = 0; c < 16; ++c) {
    const int p = c * 64 + lane;
    v[c] = ls1[h][p >> 5] + ls2[h][p & 31];
  }
  for (int r = 0; r < KNN; ++r) {
    float bv = -INFINITY; int bp = 0x7fffffff;
    #pragma unroll
    for (int c = 0; c < 16; ++c) {
      const int p = c * 64 + lane;
      if (v[c] > bv) { bv = v[c]; bp = p; }
    }
    #pragma unroll
    for (int off = 32; off > 0; off >>= 1) {
      const float ov = __shfl_xor(bv, off);
      const int op = __shfl_xor(bp, off);
      if (ov > bv || (ov == bv && op < bp)) { bv = ov; bp = op; }
    }
    if (lane == 0) {
      sels[h][r] = bv;
      seli[h][r] = li1[h][bp >> 5] * NKEYS + li2[h][bp & 31];
    }
    const int cc = bp >> 6;
    const bool mine = (bp & 63) == lane;
    #pragma unroll
    for (int c = 0; c < 16; ++c)
      if (mine && c == cc) v[c] = -INFINITY;
  }
  const float m = sels[h][0];
  const float e = (lane < 32) ? expf(sels[h][lane] - m) : 0.0f;
  float s = e;
  #pragma unroll
  for (int off = 32; off > 0; off >>= 1) s += __shfl_xor(s, off);
  if (lane < 32) {
    lw[h * 32 + lane] = e / s;
    lidx[h * 32 + lane] = seli[h][lane];
  }
  __syncthreads();
  // gather
  const int d0 = t * 4;
  float4 acc = {0.f, 0.f, 0.f, 0.f};
  #pragma unroll 8
  for (int k = 0; k < 128; ++k) {
    const float4 vv = *(const float4*)&values[(size_t)lidx[k] * VDIM + d0];
    const float ww = lw[k];
    acc.x = fmaf(ww, vv.x, acc.x);
    acc.y = fmaf(ww, vv.y, acc.y);
    acc.z = fmaf(ww, vv.z, acc.z);
    acc.w = fmaf(ww, vv.w, acc.w);
  }
  *(float4*)&out[(size_t)b * VDIM + d0] = acc;
}

extern "C" void kernel_launch(void* const* d_in, const int* in_sizes, int n_in,
                              void* d_out, int out_size, void* d_ws, size_t ws_size,
                              hipStream_t stream) {
  const float* x      = (const float*)d_in[0];
  const float* w_q    = (const float*)d_in[1];
  const float* b_q    = (const float*)d_in[2];
  const float* keys   = (const float*)d_in[3];
  const float* values = (const float*)d_in[4];
  float* out = (float*)d_out;

  char* ws = (char*)d_ws;
  _Float16* xs    = (_Float16*)(ws);                  // 2048*3072*2 = 12.6 MB
  _Float16* wqs   = (_Float16*)(ws + (16u  << 20));   // 12.6 MB
  _Float16* keyss = (_Float16*)(ws + (32u  << 20));   // 4096*768*2 = 6.3 MB
  _Float16* Qs    = (_Float16*)(ws + (40u  << 20));   // 2048*6144*2 = 25.2 MB
  float*    S     = (float*)   (ws + (68u  << 20));   // 2048*4096*4 = 32 MB
  float*    sTop  = (float*)   (ws + (100u << 20));   // 2 MB
  int*      iTop  = (int*)     (ws + (102u << 20));   // 2 MB

  split_all_kernel<<<5120, 256, 0, stream>>>(x, w_q, keys, xs, wqs, keyss);

  // GEMM1: Q'' = split(x'' @ w_q''^T + b) : M=2048, N=2048, K'=3072
  mfma_gemm<true><<<dim3(QDIM / 128, BSZ / 128, 1), 256, 34816, stream>>>(
      xs, 3 * INDIM, 0, wqs, 3 * INDIM, 0, b_q,
      nullptr, 0, 0, Qs, 3 * INDIM);
  // GEMM2: S = Q'' @ keys''^T : 8 x (M=2048, N=512, K'=768)
  mfma_gemm<false><<<dim3(NKEYS / 128, BSZ / 128, NHT), 256, 32768, stream>>>(
      Qs, 3 * HALFD * NHT, 3 * HALFD, keyss, 3 * HALFD, (long)NKEYS * 3 * HALFD, nullptr,
      S, NHT * NKEYS, NKEYS, nullptr, 3 * HALFD);

  topk1_kernel<<<BSZ * NHT, 64, 0, stream>>>(S, sTop, iTop);
  topk2_gather_kernel<<<BSZ, 256, 0, stream>>>(sTop, iTop, values, out);
}

// Round 7
// 367.470 us; speedup vs baseline: 1.2739x; 1.0260x over previous
//
#include <hip/hip_runtime.h>
#include <math.h>

#define BSZ   2048
#define INDIM 1024
#define QDIM  2048   // HEADS*K_DIM
#define NHT   8      // HEADS*2
#define NKEYS 512
#define HALFD 256
#define KNN   32
#define VDIM  1024
#define HEADS 4

typedef _Float16 v8h __attribute__((ext_vector_type(8)));
typedef _Float16 v4h __attribute__((ext_vector_type(4)));
typedef float    v4f __attribute__((ext_vector_type(4)));

// ---------- f32 -> {h, h/64, m=64*(a-h)} f16 plane split ----------
// A-side plane order: [h, h/64, m]; B-side: [h, m, h/64]
template<int KSHIFT, bool ASIDE>
__device__ __forceinline__ void split4(const float* __restrict__ in,
                                       _Float16* __restrict__ out, int i) {
  const long e0 = (long)i * 4;
  const int K = 1 << KSHIFT;
  const long r = e0 >> KSHIFT;
  const int k = (int)(e0 & (K - 1));
  const float4 a = *(const float4*)&in[e0];
  const float av[4] = {a.x, a.y, a.z, a.w};
  v4h hv, dv, mv;
  #pragma unroll
  for (int u = 0; u < 4; ++u) {
    const _Float16 hh = (_Float16)av[u];
    hv[u] = hh;
    mv[u] = (_Float16)((av[u] - (float)hh) * 64.0f);
    dv[u] = (_Float16)((float)hh * 0.015625f);
  }
  _Float16* base = out + r * (3L * K) + k;
  *(v4h*)(base)         = hv;
  *(v4h*)(base + K)     = ASIDE ? dv : mv;
  *(v4h*)(base + 2 * K) = ASIDE ? mv : dv;
}

__global__ __launch_bounds__(256) void split_all_kernel(
    const float* __restrict__ x, const float* __restrict__ wq, const float* __restrict__ ky,
    _Float16* __restrict__ xs, _Float16* __restrict__ wqs, _Float16* __restrict__ kys) {
  const int i = blockIdx.x * 256 + threadIdx.x;
  if (i < 524288)            split4<10, true >(x,  xs,  i);
  else if (i < 1048576)      split4<10, false>(wq, wqs, i - 524288);
  else                       split4<8,  false>(ky, kys, i - 1048576);
}

// ---------- async global->LDS 16B ----------
__device__ __forceinline__ void gload16(const _Float16* g, _Float16* l) {
  __builtin_amdgcn_global_load_lds(
      (const __attribute__((address_space(1))) unsigned int*)g,
      (__attribute__((address_space(3))) unsigned int*)l, 16, 0, 0);
}

#define WAITV8 asm volatile("s_waitcnt vmcnt(8)" ::: "memory")
#define WAITV4 asm volatile("s_waitcnt vmcnt(4)" ::: "memory")
#define WAITV0 asm volatile("s_waitcnt vmcnt(0)" ::: "memory")

// ---------- f16 MFMA GEMM, 128x128 tile, BK=32, 4-buffer 3-ahead pipeline ----------
// Counted vmcnt across raw barriers: loads for tiles t+2,t+3 stay in flight.
// Q_EPI: bias + 3-plane f16 epilogue (LDS-transposed, vectorized stores).
template<bool Q_EPI>
__global__ __launch_bounds__(256) void mfma_gemm(
    const _Float16* __restrict__ A, int lda, long aBS,
    const _Float16* __restrict__ B, int ldb, long bBS,
    const float* __restrict__ bias,
    float* __restrict__ Cf, int ldc, long cBS,
    _Float16* __restrict__ Cq, int K) {
  __shared__ __align__(16) char smem[65536];   // 4 bufs x (A 8KB + B 8KB)
  _Float16* sh = (_Float16*)smem;
  const int t = threadIdx.x;
  const int z = blockIdx.z;
  const _Float16* Ab = A + (size_t)z * aBS;
  const _Float16* Bb = B + (size_t)z * bBS;
  const int m0 = blockIdx.y * 128, n0 = blockIdx.x * 128;

  // staging: LDS dest linear (t*16 B within 4KB half); global source inverse-swizzled
  // swizzle: byte ^= ((byte>>7)&3)<<4
  const int o0 = t * 16;
  const int os = o0 ^ (((o0 >> 7) & 3) << 4);
  const int sr = os >> 6;            // source row within 64-row half
  const int sk = (os & 63) >> 1;     // source k element (0..31)
  const _Float16* gA0 = Ab + (size_t)(m0 + sr) * lda + sk;
  const _Float16* gA1 = Ab + (size_t)(m0 + sr + 64) * lda + sk;
  const _Float16* gB0 = Bb + (size_t)(n0 + sr) * ldb + sk;
  const _Float16* gB1 = Bb + (size_t)(n0 + sr + 64) * ldb + sk;
  const int t8 = t * 8;

  const int lane = t & 63, w = t >> 6;
  const int wr = (w >> 1) * 64, wc = (w & 1) * 64;
  const int fr = lane & 15, kg = lane >> 4;

  int aoff[4], boff[4];
  #pragma unroll
  for (int i = 0; i < 4; ++i) {
    const int ra = wr + i * 16 + fr;
    aoff[i] = (ra * 64 + ((kg ^ ((ra >> 1) & 3)) * 16)) >> 1;
    const int rb = wc + i * 16 + fr;
    boff[i] = ((rb * 64 + ((kg ^ ((rb >> 1) & 3)) * 16)) >> 1) + 4096;
  }

  v4f acc[4][4];
  #pragma unroll
  for (int i = 0; i < 4; ++i)
    #pragma unroll
    for (int j = 0; j < 4; ++j)
      acc[i][j] = (v4f){0.f, 0.f, 0.f, 0.f};

  const int nt = K >> 5;   // BK=32 tiles; nt >= 4 for all our shapes

  // prologue: stage tiles 0..2 into bufs 0..2 (12 loads in flight)
  #pragma unroll
  for (int p = 0; p < 3; ++p) {
    _Float16* bb = sh + p * 8192;
    const size_t ko = (size_t)p * 32;
    gload16(gA0 + ko, bb + t8);
    gload16(gA1 + ko, bb + 2048 + t8);
    gload16(gB0 + ko, bb + 4096 + t8);
    gload16(gB1 + ko, bb + 6144 + t8);
  }
  WAITV8;                              // tile 0 landed (all waves)
  __builtin_amdgcn_s_barrier();
  __builtin_amdgcn_sched_barrier(0);

  for (int tt = 0; tt < nt; ++tt) {
    const _Float16* bb = sh + (tt & 3) * 8192;
    if (tt + 3 < nt) {                 // stage tile tt+3 (overwrites buf read at tt-1)
      _Float16* nb = sh + ((tt + 3) & 3) * 8192;
      const size_t ko = (size_t)(tt + 3) * 32;
      gload16(gA0 + ko, nb + t8);
      gload16(gA1 + ko, nb + 2048 + t8);
      gload16(gB0 + ko, nb + 4096 + t8);
      gload16(gB1 + ko, nb + 6144 + t8);
    }
    v8h af[4], bf[4];
    #pragma unroll
    for (int i = 0; i < 4; ++i) af[i] = *(const v8h*)(bb + aoff[i]);
    #pragma unroll
    for (int j = 0; j < 4; ++j) bf[j] = *(const v8h*)(bb + boff[j]);
    #pragma unroll
    for (int i = 0; i < 4; ++i)
      #pragma unroll
      for (int j = 0; j < 4; ++j)
        acc[i][j] = __builtin_amdgcn_mfma_f32_16x16x32_f16(af[i], bf[j], acc[i][j], 0, 0, 0);
    // counted wait: tile tt+1 landed for THIS wave; barrier makes it true for ALL waves
    if (tt + 3 < nt)      { WAITV8; }
    else if (tt + 2 < nt) { WAITV4; }
    else if (tt + 1 < nt) { WAITV0; }
    __builtin_amdgcn_s_barrier();
    __builtin_amdgcn_sched_barrier(0);   // pin next iter's ds_reads after barrier
  }

  // C/D map (16x16x32): col = lane&15, row = (lane>>4)*4 + reg
  if (Q_EPI) {
    // two 64-col passes through LDS [128][68] f32 (34816 B <= 64KB)
    float* Ct = (float*)smem;
    #pragma unroll
    for (int half = 0; half < 2; ++half) {
      __syncthreads();
      if ((w & 1) == half) {
        #pragma unroll
        for (int j = 0; j < 4; ++j) {
          const int colq = j * 16 + fr;          // 0..63 within half
          const float bv = bias[n0 + half * 64 + colq];
          #pragma unroll
          for (int i = 0; i < 4; ++i)
            #pragma unroll
            for (int rr = 0; rr < 4; ++rr)
              Ct[(wr + i * 16 + kg * 4 + rr) * 68 + colq] = acc[i][j][rr] + bv;
        }
      }
      __syncthreads();
      const int r = t >> 1, cb = (t & 1) * 32;
      const int gcol = n0 + half * 64 + cb;      // 32-aligned
      const int ht = gcol >> 8, dd = gcol & 255;
      _Float16* p = Cq + (size_t)(m0 + r) * (3 * HALFD * NHT) + ht * (3 * HALFD) + dd;
      #pragma unroll
      for (int u = 0; u < 32; u += 8) {
        float vv[8];
        *(float4*)&vv[0] = *(const float4*)&Ct[r * 68 + cb + u];
        *(float4*)&vv[4] = *(const float4*)&Ct[r * 68 + cb + u + 4];
        v8h hv, dv, mv;
        #pragma unroll
        for (int e = 0; e < 8; ++e) {
          const _Float16 hh = (_Float16)vv[e];
          hv[e] = hh;
          mv[e] = (_Float16)((vv[e] - (float)hh) * 64.0f);
          dv[e] = (_Float16)((float)hh * 0.015625f);
        }
        *(v8h*)(p + u) = hv;                    // h
        *(v8h*)(p + HALFD + u) = dv;            // h/64
        *(v8h*)(p + 2 * HALFD + u) = mv;        // m
      }
    }
  } else {
    float* Cb = Cf + (size_t)z * cBS;
    #pragma unroll
    for (int i = 0; i < 4; ++i)
      #pragma unroll
      for (int j = 0; j < 4; ++j)
        #pragma unroll
        for (int rr = 0; rr < 4; ++rr) {
          const int rowg = m0 + wr + i * 16 + kg * 4 + rr;
          const int colg = n0 + wc + j * 16 + fr;
          Cb[(size_t)rowg * ldc + colg] = acc[i][j][rr];
        }
  }
}

// ---------------- top-32 of 512 per row; ties -> smallest index ----------------
__global__ __launch_bounds__(64) void topk1_kernel(
    const float* __restrict__ S, float* __restrict__ sTop, int* __restrict__ iTop) {
  const int row = blockIdx.x;           // b*8 + ht
  const int lane = threadIdx.x;
  const float* sr = S + (size_t)row * NKEYS;
  float v[8];
  #pragma unroll
  for (int j = 0; j < 8; ++j) v[j] = sr[j * 64 + lane];
  for (int r = 0; r < KNN; ++r) {
    float bv = -INFINITY; int bi = 0x7fffffff;
    #pragma unroll
    for (int j = 0; j < 8; ++j) {
      int idx = j * 64 + lane;
      if (v[j] > bv) { bv = v[j]; bi = idx; }
    }
    #pragma unroll
    for (int off = 32; off > 0; off >>= 1) {
      float ov = __shfl_xor(bv, off);
      int oi = __shfl_xor(bi, off);
      if (ov > bv || (ov == bv && oi < bi)) { bv = ov; bi = oi; }
    }
    if (lane == 0) { sTop[(size_t)row * KNN + r] = bv; iTop[(size_t)row * KNN + r] = bi; }
    const int jj = bi >> 6;
    const bool mine = (bi & 63) == lane;
    #pragma unroll
    for (int j = 0; j < 8; ++j)
      if (mine && j == jj) v[j] = -INFINITY;
  }
}

// ============ topk2 + softmax + gather fused (one block per token) ============
__global__ __launch_bounds__(256) void topk2_gather_kernel(
    const float* __restrict__ sTop, const int* __restrict__ iTop,
    const float* __restrict__ values, float* __restrict__ out) {
  __shared__ float ls1[4][32], ls2[4][32], sels[4][32];
  __shared__ int   li1[4][32], li2[4][32], seli[4][32];
  __shared__ float lw[128];
  __shared__ int   lidx[128];
  const int b = blockIdx.x, t = threadIdx.x;
  const int lane = t & 63, h = t >> 6;
  const size_t r1 = ((size_t)b * NHT + 2 * h) * KNN;
  if (lane < 32) {
    ls1[h][lane] = sTop[r1 + lane];        li1[h][lane] = iTop[r1 + lane];
    ls2[h][lane] = sTop[r1 + KNN + lane];  li2[h][lane] = iTop[r1 + KNN + lane];
  }
  float v[16];
  #pragma unroll
  for (int c = 0; c < 16; ++c) {
    const int p = c * 64 + lane;
    v[c] = ls1[h][p >> 5] + ls2[h][p & 31];
  }
  for (int r = 0; r < KNN; ++r) {
    float bv = -INFINITY; int bp = 0x7fffffff;
    #pragma unroll
    for (int c = 0; c < 16; ++c) {
      const int p = c * 64 + lane;
      if (v[c] > bv) { bv = v[c]; bp = p; }
    }
    #pragma unroll
    for (int off = 32; off > 0; off >>= 1) {
      const float ov = __shfl_xor(bv, off);
      const int op = __shfl_xor(bp, off);
      if (ov > bv || (ov == bv && op < bp)) { bv = ov; bp = op; }
    }
    if (lane == 0) {
      sels[h][r] = bv;
      seli[h][r] = li1[h][bp >> 5] * NKEYS + li2[h][bp & 31];
    }
    const int cc = bp >> 6;
    const bool mine = (bp & 63) == lane;
    #pragma unroll
    for (int c = 0; c < 16; ++c)
      if (mine && c == cc) v[c] = -INFINITY;
  }
  const float m = sels[h][0];
  const float e = (lane < 32) ? expf(sels[h][lane] - m) : 0.0f;
  float s = e;
  #pragma unroll
  for (int off = 32; off > 0; off >>= 1) s += __shfl_xor(s, off);
  if (lane < 32) {
    lw[h * 32 + lane] = e / s;
    lidx[h * 32 + lane] = seli[h][lane];
  }
  __syncthreads();
  // gather
  const int d0 = t * 4;
  float4 acc = {0.f, 0.f, 0.f, 0.f};
  #pragma unroll 8
  for (int k = 0; k < 128; ++k) {
    const float4 vv = *(const float4*)&values[(size_t)lidx[k] * VDIM + d0];
    const float ww = lw[k];
    acc.x = fmaf(ww, vv.x, acc.x);
    acc.y = fmaf(ww, vv.y, acc.y);
    acc.z = fmaf(ww, vv.z, acc.z);
    acc.w = fmaf(ww, vv.w, acc.w);
  }
  *(float4*)&out[(size_t)b * VDIM + d0] = acc;
}

extern "C" void kernel_launch(void* const* d_in, const int* in_sizes, int n_in,
                              void* d_out, int out_size, void* d_ws, size_t ws_size,
                              hipStream_t stream) {
  const float* x      = (const float*)d_in[0];
  const float* w_q    = (const float*)d_in[1];
  const float* b_q    = (const float*)d_in[2];
  const float* keys   = (const float*)d_in[3];
  const float* values = (const float*)d_in[4];
  float* out = (float*)d_out;

  char* ws = (char*)d_ws;
  _Float16* xs    = (_Float16*)(ws);                  // 2048*3072*2 = 12.6 MB
  _Float16* wqs   = (_Float16*)(ws + (16u  << 20));   // 12.6 MB
  _Float16* keyss = (_Float16*)(ws + (32u  << 20));   // 4096*768*2 = 6.3 MB
  _Float16* Qs    = (_Float16*)(ws + (40u  << 20));   // 2048*6144*2 = 25.2 MB
  float*    S     = (float*)   (ws + (68u  << 20));   // 2048*4096*4 = 32 MB
  float*    sTop  = (float*)   (ws + (100u << 20));   // 2 MB
  int*      iTop  = (int*)     (ws + (102u << 20));   // 2 MB

  split_all_kernel<<<5120, 256, 0, stream>>>(x, w_q, keys, xs, wqs, keyss);

  // GEMM1: Q'' = split(x'' @ w_q''^T + b) : M=2048, N=2048, K'=3072
  mfma_gemm<true><<<dim3(QDIM / 128, BSZ / 128, 1), 256, 0, stream>>>(
      xs, 3 * INDIM, 0, wqs, 3 * INDIM, 0, b_q,
      nullptr, 0, 0, Qs, 3 * INDIM);
  // GEMM2: S = Q'' @ keys''^T : 8 x (M=2048, N=512, K'=768)
  mfma_gemm<false><<<dim3(NKEYS / 128, BSZ / 128, NHT), 256, 0, stream>>>(
      Qs, 3 * HALFD * NHT, 3 * HALFD, keyss, 3 * HALFD, (long)NKEYS * 3 * HALFD, nullptr,
      S, NHT * NKEYS, NKEYS, nullptr, 3 * HALFD);

  topk1_kernel<<<BSZ * NHT, 64, 0, stream>>>(S, sTop, iTop);
  topk2_gather_kernel<<<BSZ, 256, 0, stream>>>(sTop, iTop, values, out);
}

// Round 8
// 333.771 us; speedup vs baseline: 1.4025x; 1.1010x over previous
//
#include <hip/hip_runtime.h>
#include <math.h>

#define BSZ   2048
#define INDIM 1024
#define QDIM  2048   // HEADS*K_DIM
#define NHT   8      // HEADS*2
#define NKEYS 512
#define HALFD 256
#define KNN   32
#define VDIM  1024
#define HEADS 4

typedef _Float16 v8h __attribute__((ext_vector_type(8)));
typedef _Float16 v4h __attribute__((ext_vector_type(4)));
typedef float    v4f __attribute__((ext_vector_type(4)));

// ---------- f32 -> {h, h/64, m=64*(a-h)} f16 plane split ----------
// A-side plane order: [h, h/64, m]; B-side: [h, m, h/64]
template<int KSHIFT, bool ASIDE>
__device__ __forceinline__ void split4(const float* __restrict__ in,
                                       _Float16* __restrict__ out, int i) {
  const long e0 = (long)i * 4;
  const int K = 1 << KSHIFT;
  const long r = e0 >> KSHIFT;
  const int k = (int)(e0 & (K - 1));
  const float4 a = *(const float4*)&in[e0];
  const float av[4] = {a.x, a.y, a.z, a.w};
  v4h hv, dv, mv;
  #pragma unroll
  for (int u = 0; u < 4; ++u) {
    const _Float16 hh = (_Float16)av[u];
    hv[u] = hh;
    mv[u] = (_Float16)((av[u] - (float)hh) * 64.0f);
    dv[u] = (_Float16)((float)hh * 0.015625f);
  }
  _Float16* base = out + r * (3L * K) + k;
  *(v4h*)(base)         = hv;
  *(v4h*)(base + K)     = ASIDE ? dv : mv;
  *(v4h*)(base + 2 * K) = ASIDE ? mv : dv;
}

__global__ __launch_bounds__(256) void split_all_kernel(
    const float* __restrict__ x, const float* __restrict__ wq, const float* __restrict__ ky,
    _Float16* __restrict__ xs, _Float16* __restrict__ wqs, _Float16* __restrict__ kys) {
  const int i = blockIdx.x * 256 + threadIdx.x;
  if (i < 524288)            split4<10, true >(x,  xs,  i);
  else if (i < 1048576)      split4<10, false>(wq, wqs, i - 524288);
  else                       split4<8,  false>(ky, kys, i - 1048576);
}

// ---------- async global->LDS 16B ----------
__device__ __forceinline__ void gload16(const _Float16* g, _Float16* l) {
  __builtin_amdgcn_global_load_lds(
      (const __attribute__((address_space(1))) unsigned int*)g,
      (__attribute__((address_space(3))) unsigned int*)l, 16, 0, 0);
}

#define WAITV8 asm volatile("s_waitcnt vmcnt(8)" ::: "memory")
#define WAITV4 asm volatile("s_waitcnt vmcnt(4)" ::: "memory")
#define WAITV0 asm volatile("s_waitcnt vmcnt(0)" ::: "memory")

// ---------- f16 MFMA GEMM, 128x128 tile, BK=32, 4-buffer 3-ahead pipeline ----------
// Counted vmcnt across raw barriers: loads for tiles t+2,t+3 stay in flight.
// Q_EPI: bias + 3-plane f16 epilogue (LDS-transposed, vectorized stores).
template<bool Q_EPI>
__global__ __launch_bounds__(256) void mfma_gemm(
    const _Float16* __restrict__ A, int lda, long aBS,
    const _Float16* __restrict__ B, int ldb, long bBS,
    const float* __restrict__ bias,
    float* __restrict__ Cf, int ldc, long cBS,
    _Float16* __restrict__ Cq, int K) {
  __shared__ __align__(16) char smem[65536];   // 4 bufs x (A 8KB + B 8KB)
  _Float16* sh = (_Float16*)smem;
  const int t = threadIdx.x;
  const int z = blockIdx.z;
  const _Float16* Ab = A + (size_t)z * aBS;
  const _Float16* Bb = B + (size_t)z * bBS;
  const int m0 = blockIdx.y * 128, n0 = blockIdx.x * 128;

  // staging: LDS dest linear (t*16 B within 4KB half); global source inverse-swizzled
  // swizzle: byte ^= ((byte>>7)&3)<<4
  const int o0 = t * 16;
  const int os = o0 ^ (((o0 >> 7) & 3) << 4);
  const int sr = os >> 6;            // source row within 64-row half
  const int sk = (os & 63) >> 1;     // source k element (0..31)
  const _Float16* gA0 = Ab + (size_t)(m0 + sr) * lda + sk;
  const _Float16* gA1 = Ab + (size_t)(m0 + sr + 64) * lda + sk;
  const _Float16* gB0 = Bb + (size_t)(n0 + sr) * ldb + sk;
  const _Float16* gB1 = Bb + (size_t)(n0 + sr + 64) * ldb + sk;
  const int t8 = t * 8;

  const int lane = t & 63, w = t >> 6;
  const int wr = (w >> 1) * 64, wc = (w & 1) * 64;
  const int fr = lane & 15, kg = lane >> 4;

  int aoff[4], boff[4];
  #pragma unroll
  for (int i = 0; i < 4; ++i) {
    const int ra = wr + i * 16 + fr;
    aoff[i] = (ra * 64 + ((kg ^ ((ra >> 1) & 3)) * 16)) >> 1;
    const int rb = wc + i * 16 + fr;
    boff[i] = ((rb * 64 + ((kg ^ ((rb >> 1) & 3)) * 16)) >> 1) + 4096;
  }

  v4f acc[4][4];
  #pragma unroll
  for (int i = 0; i < 4; ++i)
    #pragma unroll
    for (int j = 0; j < 4; ++j)
      acc[i][j] = (v4f){0.f, 0.f, 0.f, 0.f};

  const int nt = K >> 5;   // BK=32 tiles; nt >= 4 for all our shapes

  // prologue: stage tiles 0..2 into bufs 0..2 (12 loads in flight)
  #pragma unroll
  for (int p = 0; p < 3; ++p) {
    _Float16* bb = sh + p * 8192;
    const size_t ko = (size_t)p * 32;
    gload16(gA0 + ko, bb + t8);
    gload16(gA1 + ko, bb + 2048 + t8);
    gload16(gB0 + ko, bb + 4096 + t8);
    gload16(gB1 + ko, bb + 6144 + t8);
  }
  WAITV8;                              // tile 0 landed (all waves)
  __builtin_amdgcn_s_barrier();
  __builtin_amdgcn_sched_barrier(0);

  for (int tt = 0; tt < nt; ++tt) {
    const _Float16* bb = sh + (tt & 3) * 8192;
    if (tt + 3 < nt) {                 // stage tile tt+3 (overwrites buf read at tt-1)
      _Float16* nb = sh + ((tt + 3) & 3) * 8192;
      const size_t ko = (size_t)(tt + 3) * 32;
      gload16(gA0 + ko, nb + t8);
      gload16(gA1 + ko, nb + 2048 + t8);
      gload16(gB0 + ko, nb + 4096 + t8);
      gload16(gB1 + ko, nb + 6144 + t8);
    }
    v8h af[4], bf[4];
    #pragma unroll
    for (int i = 0; i < 4; ++i) af[i] = *(const v8h*)(bb + aoff[i]);
    #pragma unroll
    for (int j = 0; j < 4; ++j) bf[j] = *(const v8h*)(bb + boff[j]);
    #pragma unroll
    for (int i = 0; i < 4; ++i)
      #pragma unroll
      for (int j = 0; j < 4; ++j)
        acc[i][j] = __builtin_amdgcn_mfma_f32_16x16x32_f16(af[i], bf[j], acc[i][j], 0, 0, 0);
    // counted wait: tile tt+1 landed for THIS wave; barrier makes it true for ALL waves
    if (tt + 3 < nt)      { WAITV8; }
    else if (tt + 2 < nt) { WAITV4; }
    else if (tt + 1 < nt) { WAITV0; }
    __builtin_amdgcn_s_barrier();
    __builtin_amdgcn_sched_barrier(0);   // pin next iter's ds_reads after barrier
  }

  // C/D map (16x16x32): col = lane&15, row = (lane>>4)*4 + reg
  if (Q_EPI) {
    // two 64-col passes through LDS [128][68] f32 (34816 B <= 64KB)
    float* Ct = (float*)smem;
    #pragma unroll
    for (int half = 0; half < 2; ++half) {
      __syncthreads();
      if ((w & 1) == half) {
        #pragma unroll
        for (int j = 0; j < 4; ++j) {
          const int colq = j * 16 + fr;          // 0..63 within half
          const float bv = bias[n0 + half * 64 + colq];
          #pragma unroll
          for (int i = 0; i < 4; ++i)
            #pragma unroll
            for (int rr = 0; rr < 4; ++rr)
              Ct[(wr + i * 16 + kg * 4 + rr) * 68 + colq] = acc[i][j][rr] + bv;
        }
      }
      __syncthreads();
      const int r = t >> 1, cb = (t & 1) * 32;
      const int gcol = n0 + half * 64 + cb;      // 32-aligned
      const int ht = gcol >> 8, dd = gcol & 255;
      _Float16* p = Cq + (size_t)(m0 + r) * (3 * HALFD * NHT) + ht * (3 * HALFD) + dd;
      #pragma unroll
      for (int u = 0; u < 32; u += 8) {
        float vv[8];
        *(float4*)&vv[0] = *(const float4*)&Ct[r * 68 + cb + u];
        *(float4*)&vv[4] = *(const float4*)&Ct[r * 68 + cb + u + 4];
        v8h hv, dv, mv;
        #pragma unroll
        for (int e = 0; e < 8; ++e) {
          const _Float16 hh = (_Float16)vv[e];
          hv[e] = hh;
          mv[e] = (_Float16)((vv[e] - (float)hh) * 64.0f);
          dv[e] = (_Float16)((float)hh * 0.015625f);
        }
        *(v8h*)(p + u) = hv;                    // h
        *(v8h*)(p + HALFD + u) = dv;            // h/64
        *(v8h*)(p + 2 * HALFD + u) = mv;        // m
      }
    }
  } else {
    float* Cb = Cf + (size_t)z * cBS;
    #pragma unroll
    for (int i = 0; i < 4; ++i)
      #pragma unroll
      for (int j = 0; j < 4; ++j)
        #pragma unroll
        for (int rr = 0; rr < 4; ++rr) {
          const int rowg = m0 + wr + i * 16 + kg * 4 + rr;
          const int colg = n0 + wc + j * 16 + fr;
          Cb[(size_t)rowg * ldc + colg] = acc[i][j][rr];
        }
  }
}

// ====== topk1 (x2 rows) + topk2 + softmax + gather, one block per token ======
// Wave h handles ht rows 2h, 2h+1 (exactly the rows head h needs). Identical
// scan order / tie rules as the separate kernels => bit-identical selection.
__global__ __launch_bounds__(256) void topk_all_gather_kernel(
    const float* __restrict__ S, const float* __restrict__ values,
    float* __restrict__ out) {
  __shared__ float ls1[4][32], ls2[4][32], sels[4][32];
  __shared__ int   li1[4][32], li2[4][32], seli[4][32];
  __shared__ float lw[128];
  __shared__ int   lidx[128];
  const int b = blockIdx.x, t = threadIdx.x;
  const int lane = t & 63, h = t >> 6;
  const float* srA = S + ((size_t)b * NHT + 2 * h) * NKEYS;
  const float* srB = srA + NKEYS;
  float va[8], vb[8];
  #pragma unroll
  for (int j = 0; j < 8; ++j) va[j] = srA[j * 64 + lane];
  #pragma unroll
  for (int j = 0; j < 8; ++j) vb[j] = srB[j * 64 + lane];

  // ---- top-32 of row A (ht=2h) ----
  for (int r = 0; r < KNN; ++r) {
    float bv = -INFINITY; int bi = 0x7fffffff;
    #pragma unroll
    for (int j = 0; j < 8; ++j) {
      const int idx = j * 64 + lane;
      if (va[j] > bv) { bv = va[j]; bi = idx; }
    }
    #pragma unroll
    for (int off = 32; off > 0; off >>= 1) {
      const float ov = __shfl_xor(bv, off);
      const int oi = __shfl_xor(bi, off);
      if (ov > bv || (ov == bv && oi < bi)) { bv = ov; bi = oi; }
    }
    if (lane == 0) { ls1[h][r] = bv; li1[h][r] = bi; }
    const int jj = bi >> 6;
    const bool mine = (bi & 63) == lane;
    #pragma unroll
    for (int j = 0; j < 8; ++j)
      if (mine && j == jj) va[j] = -INFINITY;
  }
  // ---- top-32 of row B (ht=2h+1) ----
  for (int r = 0; r < KNN; ++r) {
    float bv = -INFINITY; int bi = 0x7fffffff;
    #pragma unroll
    for (int j = 0; j < 8; ++j) {
      const int idx = j * 64 + lane;
      if (vb[j] > bv) { bv = vb[j]; bi = idx; }
    }
    #pragma unroll
    for (int off = 32; off > 0; off >>= 1) {
      const float ov = __shfl_xor(bv, off);
      const int oi = __shfl_xor(bi, off);
      if (ov > bv || (ov == bv && oi < bi)) { bv = ov; bi = oi; }
    }
    if (lane == 0) { ls2[h][r] = bv; li2[h][r] = bi; }
    const int jj = bi >> 6;
    const bool mine = (bi & 63) == lane;
    #pragma unroll
    for (int j = 0; j < 8; ++j)
      if (mine && j == jj) vb[j] = -INFINITY;
  }

  // ---- cartesian top-32 of 1024 (head h) ----
  float v[16];
  #pragma unroll
  for (int c = 0; c < 16; ++c) {
    const int p = c * 64 + lane;
    v[c] = ls1[h][p >> 5] + ls2[h][p & 31];
  }
  for (int r = 0; r < KNN; ++r) {
    float bv = -INFINITY; int bp = 0x7fffffff;
    #pragma unroll
    for (int c = 0; c < 16; ++c) {
      const int p = c * 64 + lane;
      if (v[c] > bv) { bv = v[c]; bp = p; }
    }
    #pragma unroll
    for (int off = 32; off > 0; off >>= 1) {
      const float ov = __shfl_xor(bv, off);
      const int op = __shfl_xor(bp, off);
      if (ov > bv || (ov == bv && op < bp)) { bv = ov; bp = op; }
    }
    if (lane == 0) {
      sels[h][r] = bv;
      seli[h][r] = li1[h][bp >> 5] * NKEYS + li2[h][bp & 31];
    }
    const int cc = bp >> 6;
    const bool mine = (bp & 63) == lane;
    #pragma unroll
    for (int c = 0; c < 16; ++c)
      if (mine && c == cc) v[c] = -INFINITY;
  }
  const float m = sels[h][0];
  const float e = (lane < 32) ? expf(sels[h][lane] - m) : 0.0f;
  float s = e;
  #pragma unroll
  for (int off = 32; off > 0; off >>= 1) s += __shfl_xor(s, off);
  if (lane < 32) {
    lw[h * 32 + lane] = e / s;
    lidx[h * 32 + lane] = seli[h][lane];
  }
  __syncthreads();
  // ---- gather ----
  const int d0 = t * 4;
  float4 acc = {0.f, 0.f, 0.f, 0.f};
  #pragma unroll 8
  for (int k = 0; k < 128; ++k) {
    const float4 vv = *(const float4*)&values[(size_t)lidx[k] * VDIM + d0];
    const float ww = lw[k];
    acc.x = fmaf(ww, vv.x, acc.x);
    acc.y = fmaf(ww, vv.y, acc.y);
    acc.z = fmaf(ww, vv.z, acc.z);
    acc.w = fmaf(ww, vv.w, acc.w);
  }
  *(float4*)&out[(size_t)b * VDIM + d0] = acc;
}

extern "C" void kernel_launch(void* const* d_in, const int* in_sizes, int n_in,
                              void* d_out, int out_size, void* d_ws, size_t ws_size,
                              hipStream_t stream) {
  const float* x      = (const float*)d_in[0];
  const float* w_q    = (const float*)d_in[1];
  const float* b_q    = (const float*)d_in[2];
  const float* keys   = (const float*)d_in[3];
  const float* values = (const float*)d_in[4];
  float* out = (float*)d_out;

  char* ws = (char*)d_ws;
  _Float16* xs    = (_Float16*)(ws);                  // 2048*3072*2 = 12.6 MB
  _Float16* wqs   = (_Float16*)(ws + (16u  << 20));   // 12.6 MB
  _Float16* keyss = (_Float16*)(ws + (32u  << 20));   // 4096*768*2 = 6.3 MB
  _Float16* Qs    = (_Float16*)(ws + (40u  << 20));   // 2048*6144*2 = 25.2 MB
  float*    S     = (float*)   (ws + (68u  << 20));   // 2048*4096*4 = 32 MB

  split_all_kernel<<<5120, 256, 0, stream>>>(x, w_q, keys, xs, wqs, keyss);

  // GEMM1: Q'' = split(x'' @ w_q''^T + b) : M=2048, N=2048, K'=3072
  mfma_gemm<true><<<dim3(QDIM / 128, BSZ / 128, 1), 256, 0, stream>>>(
      xs, 3 * INDIM, 0, wqs, 3 * INDIM, 0, b_q,
      nullptr, 0, 0, Qs, 3 * INDIM);
  // GEMM2: S = Q'' @ keys''^T : 8 x (M=2048, N=512, K'=768)
  mfma_gemm<false><<<dim3(NKEYS / 128, BSZ / 128, NHT), 256, 0, stream>>>(
      Qs, 3 * HALFD * NHT, 3 * HALFD, keyss, 3 * HALFD, (long)NKEYS * 3 * HALFD, nullptr,
      S, NHT * NKEYS, NKEYS, nullptr, 3 * HALFD);

  topk_all_gather_kernel<<<BSZ, 256, 0, stream>>>(S, values, out);
}